// Round 8
// baseline (117.136 us; speedup 1.0000x reference)
//
#include <hip/hip_runtime.h>

// OpenBoundary neighbor list, N=8192, cutoff=5.0, max_neighbours=32.
// Outputs (int32, concat): to_idx[8192][32] | cell_indices[8192][32][3]=0 | actual_max
//
// R19: BRUTE FORCE. Cross-round accounting (R12/R15/R18) shows the cell-grid
// pipeline's cost is dominated by the single-block build (~15us: one CU
// streaming 96KB in / 128KB out is latency-capped) plus dispatch gaps; and
// both in-kernel agent-scope reduction attempts cost +16us (R18, relaxed) and
// +40us (R12, acq_rel) vs a ~3us extra dispatch. So: delete the grid.
//
// 67M pair tests at ~12 VALU ops/pair over 1024 SIMDs ~= 11us in ONE kernel
// that replaces build+query:
//   bf     (512 x 256): one wave per 4 query points; sweep all 8192 candidates
//          in 128 x 64-lane strides. Candidates arrive in ascending j, so
//          ballot-compact writes out_idx slots directly (exact argwhere order,
//          no sort, no LDS, no atomics). Full (unclamped) per-point count ->
//          plain store wavemax[p]. Fused zeroing of cell_indices slice.
//   maxred (1 x 1024): reduce 8192 counts -> actual_max (~1.5us dispatch;
//          proven cheaper than any fused agent-scope ladder).
// numpy f32 rounding preserved: no FMA, ((dx^2+dy^2)+dz^2) with _rn ops.

constexpr int   N     = 8192;
constexpr int   MAXNB = 32;
constexpr float CUT2  = 25.0f;     // 5.0^2 exact
constexpr int   BFBLOCKS = 512;    // 4 waves/block, 4 points/wave -> 8192 points

__device__ __forceinline__ int prefix_lt(unsigned long long m) {
    return __builtin_amdgcn_mbcnt_hi((unsigned int)(m >> 32),
                                     __builtin_amdgcn_mbcnt_lo((unsigned int)m, 0u));
}

// ---------- bf: brute-force neighbor scan, one wave per 4 points ----------
__global__ __launch_bounds__(256) void bf_kernel(const float* __restrict__ pos,
                                                 int* __restrict__ out_idx,
                                                 int4* __restrict__ cell4,
                                                 int* __restrict__ wavemax) {
    const int lane = threadIdx.x & 63;
    const int wave = threadIdx.x >> 6;

    // Fused zeroing of this block's cell_indices slice: 3MB/512 = 6144B = 384 int4.
    {
        const int b = (int)blockIdx.x * 384;
        cell4[b + threadIdx.x] = make_int4(0, 0, 0, 0);
        if (threadIdx.x < 128) cell4[b + 256 + threadIdx.x] = make_int4(0, 0, 0, 0);
    }

    // Wave-uniform base point (SGPR); 12 uniform floats -> s_loads.
    const int w  = __builtin_amdgcn_readfirstlane((int)blockIdx.x * 4 + wave);
    const int p0 = w * 4;
    const float qx0 = pos[3 * p0 + 0], qy0 = pos[3 * p0 + 1], qz0 = pos[3 * p0 + 2];
    const float qx1 = pos[3 * p0 + 3], qy1 = pos[3 * p0 + 4], qz1 = pos[3 * p0 + 5];
    const float qx2 = pos[3 * p0 + 6], qy2 = pos[3 * p0 + 7], qz2 = pos[3 * p0 + 8];
    const float qx3 = pos[3 * p0 + 9], qy3 = pos[3 * p0 + 10], qz3 = pos[3 * p0 + 11];

    int c0 = 0, c1 = 0, c2 = 0, c3 = 0;   // full unclamped hit counts (uniform)

    for (int base = 0; base < N; base += 64) {
        const int j = base + lane;
        // 64 consecutive candidates: 3 coalesced dword loads (768B/wave window).
        const float cx = pos[3 * j + 0];
        const float cy = pos[3 * j + 1];
        const float cz = pos[3 * j + 2];

        // numpy f32 rounding: no FMA, ((dx^2+dy^2)+dz^2). Hits within a sweep
        // are ascending in lane==j order; sweeps ascend -> exact argwhere order.
        {
            const float dx = __fsub_rn(qx0, cx), dy = __fsub_rn(qy0, cy), dz = __fsub_rn(qz0, cz);
            const float r2 = __fadd_rn(__fadd_rn(__fmul_rn(dx, dx), __fmul_rn(dy, dy)), __fmul_rn(dz, dz));
            const bool hit = (r2 <= CUT2) && (j != p0);
            const unsigned long long m = __ballot(hit);
            if (hit) { const int slot = c0 + prefix_lt(m); if (slot < MAXNB) out_idx[p0 * MAXNB + slot] = j; }
            c0 += __popcll(m);
        }
        {
            const float dx = __fsub_rn(qx1, cx), dy = __fsub_rn(qy1, cy), dz = __fsub_rn(qz1, cz);
            const float r2 = __fadd_rn(__fadd_rn(__fmul_rn(dx, dx), __fmul_rn(dy, dy)), __fmul_rn(dz, dz));
            const bool hit = (r2 <= CUT2) && (j != p0 + 1);
            const unsigned long long m = __ballot(hit);
            if (hit) { const int slot = c1 + prefix_lt(m); if (slot < MAXNB) out_idx[(p0 + 1) * MAXNB + slot] = j; }
            c1 += __popcll(m);
        }
        {
            const float dx = __fsub_rn(qx2, cx), dy = __fsub_rn(qy2, cy), dz = __fsub_rn(qz2, cz);
            const float r2 = __fadd_rn(__fadd_rn(__fmul_rn(dx, dx), __fmul_rn(dy, dy)), __fmul_rn(dz, dz));
            const bool hit = (r2 <= CUT2) && (j != p0 + 2);
            const unsigned long long m = __ballot(hit);
            if (hit) { const int slot = c2 + prefix_lt(m); if (slot < MAXNB) out_idx[(p0 + 2) * MAXNB + slot] = j; }
            c2 += __popcll(m);
        }
        {
            const float dx = __fsub_rn(qx3, cx), dy = __fsub_rn(qy3, cy), dz = __fsub_rn(qz3, cz);
            const float r2 = __fadd_rn(__fadd_rn(__fmul_rn(dx, dx), __fmul_rn(dy, dy)), __fmul_rn(dz, dz));
            const bool hit = (r2 <= CUT2) && (j != p0 + 3);
            const unsigned long long m = __ballot(hit);
            if (hit) { const int slot = c3 + prefix_lt(m); if (slot < MAXNB) out_idx[(p0 + 3) * MAXNB + slot] = j; }
            c3 += __popcll(m);
        }
    }

    // Tail fill: slots [count, 32) = -1. Counts are wave-uniform; writes go to
    // addresses never touched by the hit stores above (slot < count).
    if (lane < MAXNB) {
        if (lane >= c0) out_idx[p0 * MAXNB + lane] = -1;
        if (lane >= c1) out_idx[(p0 + 1) * MAXNB + lane] = -1;
        if (lane >= c2) out_idx[(p0 + 2) * MAXNB + lane] = -1;
        if (lane >= c3) out_idx[(p0 + 3) * MAXNB + lane] = -1;
    }

    // Full counts for actual_max; maxred (next dispatch) reduces. No atomics.
    if (lane == 0) {
        wavemax[p0]     = c0;
        wavemax[p0 + 1] = c1;
        wavemax[p0 + 2] = c2;
        wavemax[p0 + 3] = c3;
    }
}

// ---------- maxred: 1 block, reduce 8192 counts -> actual_max ----------
__global__ __launch_bounds__(1024) void maxred_kernel(const int* __restrict__ wavemax,
                                                      int* __restrict__ out_max) {
    __shared__ int wm[16];
    const int t    = threadIdx.x;
    const int lane = t & 63;
    const int wv   = t >> 6;
    const int4* w4 = (const int4*)wavemax;            // 2048 int4 = 8192 ints
    const int4 a = w4[t];
    const int4 b = w4[t + 1024];
    int mx = max(max(max(a.x, a.y), max(a.z, a.w)),
                 max(max(b.x, b.y), max(b.z, b.w)));
    #pragma unroll
    for (int off = 32; off > 0; off >>= 1) mx = max(mx, __shfl_xor(mx, off));
    if (lane == 0) wm[wv] = mx;
    __syncthreads();
    if (t == 0) {
        int m2 = wm[0];
        #pragma unroll
        for (int k = 1; k < 16; ++k) m2 = max(m2, wm[k]);
        *out_max = m2;
    }
}

extern "C" void kernel_launch(void* const* d_in, const int* in_sizes, int n_in,
                              void* d_out, int out_size, void* d_ws, size_t ws_size,
                              hipStream_t stream) {
    const float* pos = (const float*)d_in[0];   // [8192, 3] f32
    int* out = (int*)d_out;

    int*  out_idx = out;                        // [N*32]
    int4* cell4   = (int4*)(out + N * MAXNB);   // cell_indices region (zeroed by bf)
    int*  out_max = out + N * MAXNB * 4;        // scalar

    int* wavemax = (int*)d_ws;                  // 8192 ints; fully written by bf

    bf_kernel    <<<BFBLOCKS, 256, 0, stream>>>(pos, out_idx, cell4, wavemax);
    maxred_kernel<<<1, 1024, 0, stream>>>(wavemax, out_max);
}

// Round 9
// 68.458 us; speedup vs baseline: 1.7111x; 1.7111x over previous
//
#include <hip/hip_runtime.h>

// OpenBoundary neighbor list, N=8192, cutoff=5.0, max_neighbours=32.
// Outputs (int32, concat): to_idx[8192][32] | cell_indices[8192][32][3]=0 | actual_max
//
// R20 = R15 (73.25us, best) with the single-block build replaced by a
// 64-block fence-free counting sort. R19's brute force (63.7us kernel,
// VALUBusy 26%) proved pair-testing has an ~11us VALU floor + latency stalls;
// the cell pipeline stays. Accounting: fill(~40) + fixed(~12) + exec(~20).
// Exec = build ~8 (1 CU serializing 96KB in/128KB out) + query ~10 + maxred 1.5.
//
// buildp: each of 64 blocks redundantly scans ALL 8192 points (96KB, L2-cheap)
// and histograms the 64 cell-RANGES (cid>>6). All blocks therefore compute the
// IDENTICAL range histogram -> each derives the global range prefix locally
// (no cross-block communication, no atomics, no fences -- the R12/R18 lesson).
// Each block then scatters only its own range's ~128 points (its 64 cells)
// using LDS-local cell ranks. Deterministic; within-cell order is arbitrary,
// which query's bitonic sort already handles. start_g written per-block.
//
// query (2048 x 256) and maxred (1 x 1024): byte-identical to R15.

constexpr int   N     = 8192;
constexpr int   MAXNB = 32;
constexpr float CUT2  = 25.0f;     // 5.0^2 exact
constexpr int   C     = 16;        // cells/dim; width 80/16 = 5.0 == cutoff
constexpr int   NCP   = C * C * C; // 4096 cells, exact
constexpr float INVW  = 0.2f;      // 16/80; exact floor(v/5) for all f32 v in [0,80)
constexpr int   QBLOCKS = N / 4;   // 2048 query blocks (4 waves each)
constexpr int   BBLK  = 64;        // build blocks; 64 cells (one cid>>6 range) each

__device__ __forceinline__ int cell_coord(float v) {
    int c = (int)(v * INVW);
    return c > C - 1 ? C - 1 : c;  // v in [0,80): clamp boundary rounding
}

// ---------- buildp: 64-block redundant-scan counting sort, no cross-block comm ----------
__global__ __launch_bounds__(1024) void buildp_kernel(const float* __restrict__ pos,
                                                      int* __restrict__ start_g,
                                                      float4* __restrict__ sorted) {
    __shared__ int rangecnt[64];    // counts per cid>>6 range (identical in all blocks)
    __shared__ int cellcnt[64];     // counts per cell within OUR range
    __shared__ int rangestart[64];  // exclusive scan of rangecnt (global starts)
    __shared__ int cellstart[64];   // exclusive scan of cellcnt (local starts)
    const int t    = threadIdx.x;
    const int lane = t & 63;
    const int wv   = t >> 6;
    const int r0   = (int)blockIdx.x;

    if (t < 64) { rangecnt[t] = 0; cellcnt[t] = 0; }
    __syncthreads();

    float x[8], y[8], z[8];
    int cid[8], lrank[8];
    #pragma unroll
    for (int q = 0; q < 8; ++q) {            // coalesced: i = q*1024 + t
        const int i = q * 1024 + t;
        x[q] = pos[3 * i + 0];
        y[q] = pos[3 * i + 1];
        z[q] = pos[3 * i + 2];
        cid[q] = (cell_coord(z[q]) << 8) | (cell_coord(y[q]) << 4) | cell_coord(x[q]);
        atomicAdd(&rangecnt[cid[q] >> 6], 1);          // LDS atomic, 64 counters
        lrank[q] = ((cid[q] >> 6) == r0)               // rank within our range's cell
                       ? atomicAdd(&cellcnt[cid[q] & 63], 1) : -1;
    }
    __syncthreads();

    // Two independent 64-wide exclusive scans: wave 0 -> rangestart, wave 1 -> cellstart.
    if (wv == 0) {
        const int v = rangecnt[lane];
        int inc = v;
        #pragma unroll
        for (int off = 1; off < 64; off <<= 1) {
            const int u = __shfl_up(inc, off);
            if (lane >= off) inc += u;
        }
        rangestart[lane] = inc - v;
    } else if (wv == 1) {
        const int v = cellcnt[lane];
        int inc = v;
        #pragma unroll
        for (int off = 1; off < 64; off <<= 1) {
            const int u = __shfl_up(inc, off);
            if (lane >= off) inc += u;
        }
        cellstart[lane] = inc - v;
    }
    __syncthreads();

    // Global starts of our 64 cells; last block also writes the N sentinel.
    const int base = rangestart[r0];
    if (t < 64) start_g[r0 * 64 + t] = base + cellstart[t];
    if (r0 == BBLK - 1 && t == 0) start_g[NCP] = N;

    // Scatter only our range's points (~128): global pos = base + cellstart + lrank.
    #pragma unroll
    for (int q = 0; q < 8; ++q) {
        if (lrank[q] >= 0) {
            const int p = base + cellstart[cid[q] & 63] + lrank[q];
            sorted[p] = make_float4(x[q], y[q], z[q], __int_as_float(q * 1024 + t));
        }
    }
}

// ---------- query: one wave per point + fused cell_indices zeroing (R15 verbatim) ----------
__global__ __launch_bounds__(256) void query_kernel(const float* __restrict__ pos,
                                                    const float4* __restrict__ sorted,
                                                    const int* __restrict__ start_g,
                                                    int* __restrict__ out_idx,
                                                    int4* __restrict__ cell4,
                                                    int* __restrict__ wavemax) {
    __shared__ int hitbuf[4][64];  // slow path only
    const int lane = threadIdx.x & 63;
    const int wave = threadIdx.x >> 6;

    // Fused finalize part 1: zero this block's cell_indices slice (4 rows x 32 x 3
    // ints = 96 int4 = 1536 B contiguous). Independent stores, no barrier.
    if (threadIdx.x < 96) cell4[blockIdx.x * 96 + threadIdx.x] = make_int4(0, 0, 0, 0);

    // Force p (and everything derived) into SGPRs: it is wave-uniform.
    const int p = __builtin_amdgcn_readfirstlane((int)blockIdx.x * 4 + wave);

    const float x = pos[3 * p + 0];
    const float y = pos[3 * p + 1];
    const float z = pos[3 * p + 2];
    const int cx = cell_coord(x), cy = cell_coord(y), cz = cell_coord(z);
    // 3 distinct clamped rows per dim; any clamp-extra cell is >= 5.0 away in
    // that dim with strict inequality, so f32 r2 > 25 rejects all its points
    // (no duplicates, no holes; cell_coord == exact floor(v/5) for all f32 v).
    int xa = cx - 1; xa = xa < 0 ? 0 : (xa > C - 3 ? C - 3 : xa);
    int ya = cy - 1; ya = ya < 0 ? 0 : (ya > C - 3 ? C - 3 : ya);
    int za = cz - 1; za = za < 0 ? 0 : (za > C - 3 ? C - 3 : za);

    // Prefetch all 9 segment bounds (wave-uniform -> s_loads, batched).
    int bb[9], pre[10];
    pre[0] = 0;
    #pragma unroll
    for (int s = 0; s < 9; ++s) {
        const int rowb = ((za + s / 3) << 8) + ((ya + s % 3) << 4) + xa;
        bb[s] = start_g[rowb];
        pre[s + 1] = pre[s] + (start_g[rowb + 3] - bb[s]);   // 3 x-cells contiguous
    }
    const int total = pre[9];

    int count = 0;                 // full unclamped hit count
    int v = 0x7fffffff;            // sort key (INT_MAX padding)

    if (total <= 64) {
        // Fast path (~90% of waves at C=16, lambda~54): one sweep, no hitbuf.
        // The bitonic sort itself compacts hit ? j : INT_MAX into ascending order.
        int idx = 0;
        #pragma unroll
        for (int s = 0; s < 9; ++s) {
            const bool in_s = (lane >= pre[s]) && (lane < pre[s + 1]);
            idx = in_s ? (bb[s] + (lane - pre[s])) : idx;
        }
        const float4 o = sorted[idx];
        // numpy f32 rounding: no FMA, ((dx^2+dy^2)+dz^2)
        const float dx = __fsub_rn(x, o.x);
        const float dy = __fsub_rn(y, o.y);
        const float dz = __fsub_rn(z, o.z);
        const float r2 = __fadd_rn(__fadd_rn(__fmul_rn(dx, dx), __fmul_rn(dy, dy)),
                                   __fmul_rn(dz, dz));
        const int j = __float_as_int(o.w);
        const bool hit = (lane < total) && (r2 <= CUT2) && (j != p);
        count = __popcll(__ballot(hit));
        v = hit ? j : 0x7fffffff;
    } else {
        // General path: ballot-compact into per-wave LDS buffer.
        for (int base = 0; base < total; base += 64) {
            const int l = base + lane;
            int idx = 0;
            #pragma unroll
            for (int s = 0; s < 9; ++s) {
                const bool in_s = (l >= pre[s]) && (l < pre[s + 1]);
                idx = in_s ? (bb[s] + (l - pre[s])) : idx;
            }
            const float4 o = sorted[idx];
            const float dx = __fsub_rn(x, o.x);
            const float dy = __fsub_rn(y, o.y);
            const float dz = __fsub_rn(z, o.z);
            const float r2 = __fadd_rn(__fadd_rn(__fmul_rn(dx, dx), __fmul_rn(dy, dy)),
                                       __fmul_rn(dz, dz));
            const int j = __float_as_int(o.w);
            const bool hit = (l < total) && (r2 <= CUT2) && (j != p);
            const unsigned long long m = __ballot(hit);
            if (hit) {
                const int pr = __builtin_amdgcn_mbcnt_hi(
                    (unsigned int)(m >> 32),
                    __builtin_amdgcn_mbcnt_lo((unsigned int)m, 0u));
                const int slot = count + pr;
                if (slot < 64) hitbuf[wave][slot] = j;
            }
            count += __popcll(m);
        }
        const int mcount = count < 64 ? count : 64;
        v = (lane < mcount) ? hitbuf[wave][lane] : 0x7fffffff;
    }

    // 64-lane bitonic sort ascending -> exact argwhere order.
    #pragma unroll
    for (int k = 2; k <= 64; k <<= 1) {
        #pragma unroll
        for (int jj = k >> 1; jj >= 1; jj >>= 1) {
            const int pv = __shfl_xor(v, jj);
            const bool keepmin = ((lane & jj) == 0) == ((lane & k) == 0);
            v = keepmin ? min(v, pv) : max(v, pv);
        }
    }
    if (lane < MAXNB) out_idx[p * MAXNB + lane] = (lane < count) ? v : -1;

    // Plain store of the full count; maxred (next dispatch, same stream)
    // reduces. No atomics, no fences, no block barrier.
    if (lane == 0) wavemax[p] = count;
}

// ---------- maxred: 1 block, reduce 8192 wave counts -> actual_max ----------
__global__ __launch_bounds__(1024) void maxred_kernel(const int* __restrict__ wavemax,
                                                      int* __restrict__ out_max) {
    __shared__ int wm[16];
    const int t    = threadIdx.x;
    const int lane = t & 63;
    const int wv   = t >> 6;
    const int4* w4 = (const int4*)wavemax;            // 2048 int4 = 8192 ints
    const int4 a = w4[t];
    const int4 b = w4[t + 1024];
    int mx = max(max(max(a.x, a.y), max(a.z, a.w)),
                 max(max(b.x, b.y), max(b.z, b.w)));
    #pragma unroll
    for (int off = 32; off > 0; off >>= 1) mx = max(mx, __shfl_xor(mx, off));
    if (lane == 0) wm[wv] = mx;
    __syncthreads();
    if (t == 0) {
        int m2 = wm[0];
        #pragma unroll
        for (int k = 1; k < 16; ++k) m2 = max(m2, wm[k]);
        *out_max = m2;
    }
}

extern "C" void kernel_launch(void* const* d_in, const int* in_sizes, int n_in,
                              void* d_out, int out_size, void* d_ws, size_t ws_size,
                              hipStream_t stream) {
    const float* pos = (const float*)d_in[0];   // [8192, 3] f32
    int* out = (int*)d_out;

    int*  out_idx = out;                        // [N*32]
    int4* cell4   = (int4*)(out + N * MAXNB);   // cell_indices region (zeroed by query)
    int*  out_max = out + N * MAXNB * 4;        // scalar

    // Scratch in d_ws (~181 KB used; the 256 MiB ws poison fill shows it is
    // far larger). Every byte used is written before read within each replay.
    char*   ws      = (char*)d_ws;
    float4* sorted  = (float4*)ws;              // 131072 B, 16B aligned
    int*    start_g = (int*)(ws + 131072);      // 4097 ints
    int*    wavemax = (int*)(ws + 147968);      // 8192 ints, 16B aligned

    buildp_kernel<<<BBLK, 1024, 0, stream>>>(pos, start_g, sorted);
    query_kernel <<<QBLOCKS, 256, 0, stream>>>(pos, sorted, start_g, out_idx, cell4, wavemax);
    maxred_kernel<<<1, 1024, 0, stream>>>(wavemax, out_max);
}